// Round 11
// baseline (95.807 us; speedup 1.0000x reference)
//
#include <hip/hip_runtime.h>

#define C_LENX 2048
#define Q_LENX 512
#define BATCH  32
#define HDIM   256
#define BH     8192
#define CBLK   64
#define QBLK   32
#define NQT    16
#define TILE_BYTES 32768      // qf 16K (fp16[32][256], swz) + qt 16K (fp16[256][32], swz)
#define OFF_QT 16384
#define P_PITCH 40            // shorts; 80 B row pitch (16B-multiple, conflict-light)

typedef __attribute__((ext_vector_type(8))) _Float16 f16x8;
typedef __attribute__((ext_vector_type(4))) float f32x4;

__device__ __forceinline__ unsigned short f2h_bits(float x) {
    union { _Float16 h; unsigned short u; } cv;
    cv.h = (_Float16)x;                     // RTNE
    return cv.u;
}
__device__ __forceinline__ float h2f_bits(unsigned short u) {
    union { unsigned short u; _Float16 h; } cv;
    cv.u = u;
    return (float)cv.h;
}

// async global->LDS, 16B per lane, wave-uniform LDS base + lane*16
__device__ __forceinline__ void stage16(const void* gsrc, void* ldst) {
    __builtin_amdgcn_global_load_lds(
        (const __attribute__((address_space(1))) unsigned int*)gsrc,
        (__attribute__((address_space(3))) unsigned int*)ldst, 16, 0, 0);
}

// ---------------- prep: fp32 Q -> fp16 blob (exact swizzled LDS images) ----------------
// qf: row q (512B); 16B chunk c at byte q*512 + 16*(c ^ (q&7))     [holds Q[q][8c..8c+7]]
// qt: chunk m = h*4 + qc (qc = q/8) at byte OFF_QT + 16*(m ^ ((m>>3)&7))
__global__ __launch_bounds__(256)
void q_prep(const float* __restrict__ question, unsigned char* __restrict__ blob)
{
    __shared__ unsigned short sHf[QBLK][264];
    const int tid = threadIdx.x;
    const int b  = blockIdx.x >> 4;
    const int t  = blockIdx.x & 15;
    const float* qbase = question + (size_t)(t * QBLK) * BH + b * HDIM;
    unsigned char* tb = blob + (size_t)(b * NQT + t) * TILE_BYTES;

    #pragma unroll
    for (int i = 0; i < 8; ++i) {
        int e  = tid + i * 256;          // float4 cell 0..2047
        int qr = e >> 6;                 // 0..31
        int h4 = (e & 63) << 2;          // 0..252
        float4 x = *reinterpret_cast<const float4*>(qbase + (size_t)qr * BH + h4);
        ushort4 hv;
        hv.x = f2h_bits(x.x); hv.y = f2h_bits(x.y);
        hv.z = f2h_bits(x.z); hv.w = f2h_bits(x.w);
        *reinterpret_cast<ushort4*>(&sHf[qr][h4]) = hv;
        int c = h4 >> 3;                 // 16B chunk within row
        *reinterpret_cast<ushort4*>(tb + qr * 512 + ((c ^ (qr & 7)) << 4) + ((h4 & 7) << 1)) = hv;
    }
    __syncthreads();
    #pragma unroll
    for (int i = 0; i < 8; ++i) {
        int e  = tid + i * 256;          // ushort4 cell of qt, 0..2047
        int h  = e >> 3;                 // 0..255
        int q4 = (e & 7) << 2;           // 0..28
        ushort4 v;
        v.x = sHf[q4 + 0][h]; v.y = sHf[q4 + 1][h];
        v.z = sHf[q4 + 2][h]; v.w = sHf[q4 + 3][h];
        int m  = h * 4 + (q4 >> 3);
        int ms = m ^ ((m >> 3) & 7);
        *reinterpret_cast<ushort4*>(tb + OFF_QT + (ms << 4) + ((q4 & 4) << 1)) = v;
    }
}

// ------- main: single-fp16 QK^T (c-split), PV h-quarter-split via LDS-P, raw B_mid -------
__global__ __launch_bounds__(256, 2)
void s2s_attn(const float* __restrict__ content,
              const unsigned char* __restrict__ blob,
              const int*   __restrict__ qmask,
              float*       __restrict__ out)
{
    __shared__ __attribute__((aligned(16))) unsigned char sBuf[2 * TILE_BYTES];
    __shared__ __attribute__((aligned(16))) unsigned short sP[4][16][P_PITCH]; // P[c][q] per c-chunk
    __shared__ __attribute__((aligned(16))) float sScl[64];
    __shared__ __attribute__((aligned(16))) float sLfin[64];
    __shared__ unsigned sFlag;

    const int tid  = threadIdx.x;
    const int wid  = tid >> 6;
    const int lane = tid & 63;
    const int lr   = lane & 15;
    const int lg   = lane >> 4;

    // XCD-aware swizzle: each XCD owns 4 complete batches (blob L2 locality)
    const int lin = (blockIdx.x & 7) * 128 + (blockIdx.x >> 3);
    const int ct = lin & 31;
    const int b  = lin >> 5;
    const int c0 = ct * CBLK;

    // prologue: DMA tile 0 into buffer 0 (32 segs of 1KB; 8 per wave)
    {
        const unsigned char* tb0 = blob + (size_t)(b * NQT) * TILE_BYTES;
        #pragma unroll
        for (int j = 0; j < 8; ++j) {
            int seg = wid * 8 + j;
            stage16(tb0 + seg * 1024 + lane * 16, sBuf + seg * 1024);
        }
    }

    // content preload: 16 c-rows as single fp16 fragments (A/B-frag layout: row=lr, k=lg*8)
    f16x8 chi[8];
    {
        const float* cbase = content + (size_t)(c0 + wid*16 + lr) * BH + b*HDIM + lg*8;
        #pragma unroll
        for (int kc = 0; kc < 8; ++kc) {
            float4 x0 = *reinterpret_cast<const float4*>(cbase + kc*32);
            float4 x1 = *reinterpret_cast<const float4*>(cbase + kc*32 + 4);
            float xs[8] = {x0.x,x0.y,x0.z,x0.w,x1.x,x1.y,x1.z,x1.w};
            #pragma unroll
            for (int j = 0; j < 8; ++j)
                chi[kc][j] = (_Float16)xs[j];
        }
    }

    // acc[cc][hb]: c-chunk cc (rows cc*16+lg*4+r), h-block wid*64+hb*16+lr
    f32x4 acc[4][4];
    #pragma unroll
    for (int cc = 0; cc < 4; ++cc)
        #pragma unroll
        for (int hb = 0; hb < 4; ++hb) { f32x4 z = {0.f,0.f,0.f,0.f}; acc[cc][hb] = z; }
    float m_run = -INFINITY;   // softmax state for own c-row (c0+wid*16+lr), replicated over lg
    float l_run = 0.f;

    __syncthreads();           // tile 0 DMA drained + visible

    for (int t = 0; t < NQT; ++t) {
        const unsigned char* qf = sBuf + (t & 1) * TILE_BYTES;
        const unsigned char* qt = qf + OFF_QT;

        // issue next tile's DMA into the other buffer; stays in flight across raw B_mid,
        // drained at the end-of-tile __syncthreads (full-tile cover, R8-verified timing)
        if (t + 1 < NQT) {
            const unsigned char* tbn = blob + (size_t)(b * NQT + t + 1) * TILE_BYTES;
            unsigned char* db = sBuf + ((t + 1) & 1) * TILE_BYTES;
            #pragma unroll
            for (int j = 0; j < 8; ++j) {
                int seg = wid * 8 + j;
                stage16(tbn + seg * 1024 + lane * 16, db + seg * 1024);
            }
        }
        const unsigned mw = (unsigned)__ballot(qmask[b * Q_LENX + t * QBLK + (lane & 31)] != 0);

        // ---- swapped QK^T: S^T = mfma(A=Q, B=C); 2 independent chains, single fp16 ----
        f32x4 zz = {0.f,0.f,0.f,0.f};
        f32x4 sacc0 = zz, sacc1 = zz;
        const unsigned swz = (unsigned)(lr & 7);   // (16+lr)&7 == lr&7
        __builtin_amdgcn_s_setprio(1);
        #pragma unroll
        for (int kc = 0; kc < 8; ++kc) {
            unsigned off = (unsigned)((kc*4 + lg) ^ swz) << 4;
            f16x8 qf0 = *reinterpret_cast<const f16x8*>(qf + lr*512 + off);
            f16x8 qf1 = *reinterpret_cast<const f16x8*>(qf + (16+lr)*512 + off);
            sacc0 = __builtin_amdgcn_mfma_f32_16x16x32_f16(qf0, chi[kc], sacc0, 0, 0, 0);
            sacc1 = __builtin_amdgcn_mfma_f32_16x16x32_f16(qf1, chi[kc], sacc1, 0, 0, 0);
        }
        __builtin_amdgcn_s_setprio(0);
        // sacc0: rows q=lg*4+r, col c=lr;  sacc1: rows q=16+lg*4+r, col c=lr

        // ---- per-lane softmax for own c-row (reduce over lanes lr, lr+16, lr+32, lr+48) ----
        float p[8];
        float tmax = -INFINITY;
        #pragma unroll
        for (int r = 0; r < 4; ++r) {
            float v0 = ((mw >> (lg*4 + r))      & 1u) ? sacc0[r] : -INFINITY;
            float v1 = ((mw >> (16 + lg*4 + r)) & 1u) ? sacc1[r] : -INFINITY;
            p[r] = v0; p[4 + r] = v1;
            tmax = fmaxf(tmax, fmaxf(v0, v1));
        }
        tmax = fmaxf(tmax, __shfl_xor(tmax, 16, 64));
        tmax = fmaxf(tmax, __shfl_xor(tmax, 32, 64));

        unsigned long long bal = __ballot(tmax > m_run + 4.0f);   // T13 defer-max
        float scale = 1.f;
        if (bal) {
            float mnew = fmaxf(m_run, tmax);
            if (mnew != -INFINITY) { scale = __expf(m_run - mnew); m_run = mnew; }
            l_run *= scale;
        }

        unsigned short pb[8];
        float psum = 0.f;
        if (m_run == -INFINITY) {
            #pragma unroll
            for (int i = 0; i < 8; ++i) pb[i] = 0;
        } else {
            #pragma unroll
            for (int i = 0; i < 8; ++i) {
                float e = __expf(p[i] - m_run);    // bounded by e^4
                pb[i] = f2h_bits(e);
                psum += h2f_bits(pb[i]);           // sum ROUNDED weights
            }
        }
        psum += __shfl_xor(psum, 16, 64);
        psum += __shfl_xor(psum, 32, 64);
        l_run += psum;

        // ---- publish P[c][q] for own c-chunk + per-tile scale + rescale flag ----
        {
            ushort4 w0, w1;
            w0.x = pb[0]; w0.y = pb[1]; w0.z = pb[2]; w0.w = pb[3];
            w1.x = pb[4]; w1.y = pb[5]; w1.z = pb[6]; w1.w = pb[7];
            *reinterpret_cast<ushort4*>(&sP[wid][lr][lg*4])      = w0;  // q = lg*4..+3
            *reinterpret_cast<ushort4*>(&sP[wid][lr][16 + lg*4]) = w1;  // q = 16+lg*4..+3
        }
        if (lg == 0) sScl[wid*16 + lr] = scale;
        if (lane == 0) ((volatile unsigned char*)&sFlag)[wid] = bal ? 1 : 0;

        // ---- B_mid: raw barrier, LDS-visibility only (DMA stays in flight) ----
        asm volatile("s_waitcnt lgkmcnt(0)" ::: "memory");
        __builtin_amdgcn_s_barrier();
        asm volatile("" ::: "memory");
        __builtin_amdgcn_sched_barrier(0);

        // ---- rescale all-c acc with published scales (block-uniform skip when deferred) ----
        unsigned fw = *((volatile unsigned*)&sFlag);
        if (fw) {
            #pragma unroll
            for (int cc = 0; cc < 4; ++cc) {
                f32x4 sc = *reinterpret_cast<const f32x4*>(&sScl[cc*16 + lg*4]);
                #pragma unroll
                for (int hb = 0; hb < 4; ++hb)
                    acc[cc][hb] *= sc;
            }
        }

        // ---- PV (h-quarter split): out[64 c][64 h of this wave] += P(64x32)*Q(32x64) ----
        f16x8 vf[4];
        #pragma unroll
        for (int hb = 0; hb < 4; ++hb) {
            int h = wid*64 + hb*16 + lr;
            int m = h*4 + lg;
            int ms = m ^ ((m >> 3) & 7);
            vf[hb] = *reinterpret_cast<const f16x8*>(qt + (ms << 4));
        }
        __builtin_amdgcn_s_setprio(1);
        #pragma unroll
        for (int cc = 0; cc < 4; ++cc) {
            f16x8 pf = *reinterpret_cast<const f16x8*>(&sP[cc][lr][lg*8]);  // A[c=lr][q=lg*8..+7]
            #pragma unroll
            for (int hb = 0; hb < 4; ++hb)
                acc[cc][hb] = __builtin_amdgcn_mfma_f32_16x16x32_f16(pf, vf[hb], acc[cc][hb], 0, 0, 0);
        }
        __builtin_amdgcn_s_setprio(0);

        __syncthreads();   // B_end: all waves done with tile t; next tile's DMA drained
    }

    // ---- epilogue: publish l_run, normalize all-c acc, store ----
    if (lg == 0) sLfin[wid*16 + lr] = l_run;
    __syncthreads();
    float rinv[4][4];
    #pragma unroll
    for (int cc = 0; cc < 4; ++cc) {
        f32x4 lv = *reinterpret_cast<const f32x4*>(&sLfin[cc*16 + lg*4]);
        #pragma unroll
        for (int r = 0; r < 4; ++r) rinv[cc][r] = 1.f / lv[r];
    }
    float* obase = out + (size_t)c0 * BH + b*HDIM + wid*64;
    #pragma unroll
    for (int cc = 0; cc < 4; ++cc)
        #pragma unroll
        for (int hb = 0; hb < 4; ++hb)
            #pragma unroll
            for (int r = 0; r < 4; ++r)
                obase[(size_t)(cc*16 + lg*4 + r) * BH + hb*16 + lr] = acc[cc][hb][r] * rinv[cc][r];
}

extern "C" void kernel_launch(void* const* d_in, const int* in_sizes, int n_in,
                              void* d_out, int out_size, void* d_ws, size_t ws_size,
                              hipStream_t stream) {
    const float* content  = (const float*)d_in[0];
    const float* question = (const float*)d_in[1];
    const int*   mask     = (const int*)d_in[2];
    float*       out      = (float*)d_out;

    unsigned char* blob = (unsigned char*)d_ws;   // 512 tiles * 32KB = 16 MB

    q_prep<<<BATCH * NQT, 256, 0, stream>>>(question, blob);
    s2s_attn<<<C_LENX / CBLK * BATCH, 256, 0, stream>>>(content, blob, mask, out);
}